// Round 12
// baseline (61.308 us; speedup 1.0000x reference)
//
#include <hip/hip_runtime.h>

#define NN 2048
#define NH 4
#define COLS 256   // NH*F_OUT

typedef __attribute__((ext_vector_type(8))) short short8;
typedef __attribute__((ext_vector_type(4))) float f32x4;
typedef __attribute__((ext_vector_type(4))) int i32x4;
typedef __attribute__((ext_vector_type(4))) unsigned u32x4;

__device__ __forceinline__ unsigned cvtpk(float lo, float hi) {
  unsigned r;
  asm("v_cvt_pk_bf16_f32 %0, %1, %2" : "=v"(r) : "v"(lo), "v"(hi));
  return r;
}
__device__ __forceinline__ unsigned pack16(i32x4 a, i32x4 b, i32x4 c, i32x4 d) {
  unsigned m = 0;
  #pragma unroll
  for (int e = 0; e < 4; ++e) {
    m |= (a[e] != 0 ? 1u : 0u) << e;
    m |= (b[e] != 0 ? 1u : 0u) << (e + 4);
    m |= (c[e] != 0 ? 1u : 0u) << (e + 8);
    m |= (d[e] != 0 ? 1u : 0u) << (e + 12);
  }
  return m;
}
// async global->LDS DMA, 16B/lane: LDS dest = wave-uniform base + lane*16,
// global src = per-lane address. Needs ZERO VGPRs to keep data in flight.
__device__ __forceinline__ void gload_lds16(const void* g, void* l) {
  __builtin_amdgcn_global_load_lds(
      (const __attribute__((address_space(1))) void*)g,
      (__attribute__((address_space(3))) void*)l, 16, 0, 0);
}

// ---------------------------------------------------------------------------
// Kernel 1: h = X @ W (f32 accum). grid 1024 x 256, 8 rows/block.
//   hB : bf16, MFMA B-fragment-contiguous:
//        chunk = ((bh*64 + jc)*4 + t)*64 + (grp*16 + fl), 8 ushorts/chunk
//        holds h[n = jc*32+grp*8+e][f = t*16+fl].
//   s_src/s_dst : f32 [bh][n], PRE-SCALED by log2(e).
// ---------------------------------------------------------------------------
__global__ __launch_bounds__(256) void k1_prep(
    const float* __restrict__ nf, const float* __restrict__ W,
    const float* __restrict__ att, ushort* __restrict__ hB,
    float* __restrict__ s_src, float* __restrict__ s_dst)
{
  const int tid = threadIdx.x;
  const int head = tid >> 6, lane = tid & 63;
  const int bid = blockIdx.x;
  const int m0 = bid * 8;

  float w[64];
  #pragma unroll
  for (int f = 0; f < 64; ++f) w[f] = W[f * COLS + tid];   // coalesced

  const float LOG2E = 1.4426950408889634f;
  const float asrc = att[head * 128 + lane] * LOG2E;
  const float adst = att[head * 128 + 64 + lane] * LOG2E;

  __shared__ float xs[512];
  xs[tid]       = nf[m0 * 64 + tid];
  xs[tid + 256] = nf[m0 * 64 + 256 + tid];
  __syncthreads();

  float hv[8];
  #pragma unroll
  for (int rr = 0; rr < 8; ++rr) {
    float acc = 0.f;
    #pragma unroll
    for (int f = 0; f < 64; ++f) acc = fmaf(xs[rr * 64 + f], w[f], acc);
    hv[rr] = acc;
    float vs = acc * asrc, vd = acc * adst;
    #pragma unroll
    for (int off = 32; off > 0; off >>= 1) {
      vs += __shfl_xor(vs, off);
      vd += __shfl_xor(vd, off);
    }
    if (lane == 0) {
      const int m = m0 + rr;
      const int b = m >> 11, n = m & (NN - 1);
      s_src[(b * NH + head) * NN + n] = vs;
      s_dst[(b * NH + head) * NN + n] = vd;
    }
  }

  const int b   = m0 >> 11;
  const int n0  = m0 & (NN - 1);
  const int jc  = n0 >> 5;
  const int grp = (n0 >> 3) & 3;
  const int t   = (tid >> 4) & 3, fl = tid & 15;
  uint4 vv;
  vv.x = cvtpk(hv[0], hv[1]);
  vv.y = cvtpk(hv[2], hv[3]);
  vv.z = cvtpk(hv[4], hv[5]);
  vv.w = cvtpk(hv[6], hv[7]);
  const size_t chunk =
      (((size_t)(b * NH + head) * 64 + jc) * 4 + t) * 64 + (grp * 16 + fl);
  *(uint4*)(hB + chunk * 8) = vv;
}

// ---------------------------------------------------------------------------
// Kernel 2: fused mask + leakyrelu + softmax + P@H via MFMA 16x16x32 bf16.
// grid 512 x 256 thr (4 waves = 4 heads); 16 i-rows/block; NO j-split ->
// no cross-wave reduction. 70KB LDS -> 2 blocks/CU -> occupancy target
// 2 waves/SIMD -> VGPR budget 256 (kills the r8-r11 register starvation).
// Main loop is BARRIER-FREE and wave-autonomous:
//   vmcnt(4) -> ds_read hb/sd/mask -> lgkmcnt(0) -> DMA-stage jc+2 ->
//   exp chain -> 5 MFMA.   hB arrives via global_load_lds (0 VGPR cost).
// ---------------------------------------------------------------------------
__global__ __launch_bounds__(256) void k2_main(
    const int* __restrict__ adj, const ushort* __restrict__ hB,
    const float* __restrict__ s_src, const float* __restrict__ s_dst,
    float* __restrict__ out)
{
  const int tid = threadIdx.x;
  const int h   = tid >> 6;           // head == wave
  const int l   = tid & 63;
  const int L   = blockIdx.x;
  const int xcd  = L & 7, pos = L >> 3;          // XCD swizzle: 2 XCDs/batch
  const int b    = xcd >> 1;
  const int iblk = (xcd & 1) * 64 + pos;         // bijective over [0,128)
  const int i0   = iblk << 4;

  const int bh   = b * NH + h;
  const int r16  = l & 15;
  const int grp  = l >> 4;
  const int koff = grp << 3;

  __shared__ ushort  hbuf[NH][2][2048];   // 32KB wave-private double buffers
  __shared__ float   sdl[NH][NN];         // 32KB staged s_dst rows
  __shared__ unsigned abits[16][65];      // 4.2KB adj bit-masks, padded

  // ---- stage adj -> bits: thread = (row = tid>>4, seg = tid&15 of 128 j)
  {
    const int srow = tid >> 4, sseg = tid & 15;
    const int* sb = adj + ((size_t)(b * NN + i0 + srow)) * NN + sseg * 128;
    #pragma unroll
    for (int p = 0; p < 4; ++p) {
      const i32x4 a0 = *(const i32x4*)(sb + p * 32);
      const i32x4 a1 = *(const i32x4*)(sb + p * 32 + 4);
      const i32x4 a2 = *(const i32x4*)(sb + p * 32 + 8);
      const i32x4 a3 = *(const i32x4*)(sb + p * 32 + 12);
      const i32x4 a4 = *(const i32x4*)(sb + p * 32 + 16);
      const i32x4 a5 = *(const i32x4*)(sb + p * 32 + 20);
      const i32x4 a6 = *(const i32x4*)(sb + p * 32 + 24);
      const i32x4 a7 = *(const i32x4*)(sb + p * 32 + 28);
      const unsigned lo = pack16(a0, a1, a2, a3);
      const unsigned hi = pack16(a4, a5, a6, a7);
      abits[srow][sseg * 4 + p] = lo | (hi << 16);
    }
  }
  // ---- stage s_dst rows (all 4 heads) into LDS
  {
    const int sh = tid >> 6, sc = tid & 63;
    const float* sp = s_dst + (size_t)(b * NH + sh) * NN + sc * 32;
    float* dp = &sdl[sh][sc * 32];
    #pragma unroll
    for (int k = 0; k < 8; ++k)
      *(f32x4*)(dp + k * 4) = *(const f32x4*)(sp + k * 4);
  }
  __syncthreads();

  const float ssl = s_src[bh * NN + i0 + r16];
  const ushort* hbSrc = hB + (size_t)bh * 131072 + l * 8;

  const short8 ones = {(short)0x3F80, (short)0x3F80, (short)0x3F80, (short)0x3F80,
                       (short)0x3F80, (short)0x3F80, (short)0x3F80, (short)0x3F80};

  f32x4 acc[4];
  #pragma unroll
  for (int q = 0; q < 4; ++q) acc[q] = (f32x4){0.f, 0.f, 0.f, 0.f};
  f32x4 acd = (f32x4){0.f, 0.f, 0.f, 0.f};

#define STAGE(JC, BUF)                                                   \
  {                                                                      \
    _Pragma("unroll")                                                    \
    for (int t = 0; t < 4; ++t)                                          \
      gload_lds16(hbSrc + (JC) * 2048 + t * 512, &hbuf[h][(BUF)][t * 512]); \
  }

  // prologue: stage jc = 0, 1
  STAGE(0, 0);
  STAGE(1, 1);

  #pragma unroll 1
  for (int jc = 0; jc < 64; ++jc) {
    const int buf = jc & 1;
    // stage(jc) complete when <=4 of our VMEM ops remain (stage jc+1)
    asm volatile("s_waitcnt vmcnt(4)" ::: "memory");

    const short8 hb0 = *(const short8*)&hbuf[h][buf][l * 8];
    const short8 hb1 = *(const short8*)&hbuf[h][buf][512 + l * 8];
    const short8 hb2 = *(const short8*)&hbuf[h][buf][1024 + l * 8];
    const short8 hb3 = *(const short8*)&hbuf[h][buf][1536 + l * 8];
    const int jb = jc * 32 + koff;
    const f32x4 sd0 = *(const f32x4*)&sdl[h][jb];
    const f32x4 sd1 = *(const f32x4*)&sdl[h][jb + 4];
    const unsigned msk = abits[r16][jc] >> koff;

    // buffer free to overwrite once ds_reads retired
    asm volatile("s_waitcnt lgkmcnt(0)" ::: "memory");
    __builtin_amdgcn_sched_barrier(0);
    if (jc < 62) STAGE(jc + 2, buf);

    float pl[8];
    #pragma unroll
    for (int e = 0; e < 8; ++e) {
      const float sdv = (e < 4) ? sd0[e] : sd1[e - 4];
      float x = ssl + sdv;                 // pre-scaled by log2(e)
      x = fmaxf(x, 0.2f * x);
      const float p = __builtin_amdgcn_exp2f(x);
      pl[e] = ((msk >> e) & 1u) ? p : 0.f;
    }
    u32x4 pa;
    #pragma unroll
    for (int e2 = 0; e2 < 4; ++e2) pa[e2] = cvtpk(pl[2 * e2], pl[2 * e2 + 1]);
    union { u32x4 u; short8 s; } ca; ca.u = pa;
    const short8 pal = ca.s;

    acc[0] = __builtin_amdgcn_mfma_f32_16x16x32_bf16(pal, hb0, acc[0], 0, 0, 0);
    acc[1] = __builtin_amdgcn_mfma_f32_16x16x32_bf16(pal, hb1, acc[1], 0, 0, 0);
    acc[2] = __builtin_amdgcn_mfma_f32_16x16x32_bf16(pal, hb2, acc[2], 0, 0, 0);
    acc[3] = __builtin_amdgcn_mfma_f32_16x16x32_bf16(pal, hb3, acc[3], 0, 0, 0);
    acd    = __builtin_amdgcn_mfma_f32_16x16x32_bf16(pal, ones,    acd,    0, 0, 0);
  }
#undef STAGE

  // ---- epilogue: no cross-wave reduction needed (full j per wave)
  float rl[4];
  #pragma unroll
  for (int r = 0; r < 4; ++r) rl[r] = 1.0f / acd[r];
  #pragma unroll
  for (int t = 0; t < 4; ++t) {
    #pragma unroll
    for (int r = 0; r < 4; ++r) {
      const int i = i0 + grp * 4 + r;
      const size_t oidx = ((size_t)(b * NN + i) * COLS) + h * 64 + t * 16 + r16;
      out[oidx] = acc[t][r] * rl[r];
    }
  }
}

// ---------------------------------------------------------------------------
extern "C" void kernel_launch(void* const* d_in, const int* in_sizes, int n_in,
                              void* d_out, int out_size, void* d_ws, size_t ws_size,
                              hipStream_t stream) {
  const float* nf  = (const float*)d_in[0];
  const int*   adj = (const int*)d_in[1];
  const float* W   = (const float*)d_in[2];
  const float* att = (const float*)d_in[3];

  ushort* hB    = (ushort*)d_ws;                                  // 4 MB
  float*  s_src = (float*)((char*)d_ws + (size_t)16 * 64 * NN * 2);
  float*  s_dst = s_src + 16 * NN;

  hipLaunchKernelGGL(k1_prep, dim3(1024), dim3(256), 0, stream,
                     nf, W, att, hB, s_src, s_dst);
  hipLaunchKernelGGL(k2_main, dim3(512), dim3(256), 0, stream,
                     adj, hB, s_src, s_dst, (float*)d_out);
}